// Round 4
// baseline (135.573 us; speedup 1.0000x reference)
//
#include <hip/hip_runtime.h>
#include <hip/hip_bf16.h>

// out[b, p] = x[b, ii[p]] * x[b, jj[p]], (ii,jj)=triu_indices(512), row-major.
// Write-BW-bound: ~538 MB out, 2 MB in. Flat float4-group output indexing with
// triangular inversion. No LDS: the 2 KB batch row lives in L1 (20x reuse per
// block); j-reads are coalesced scalar dword loads, i-read is an L1 broadcast.
// This cuts per-iteration VALU from ~45 to ~25 insts (R3 was VALU-issue-bound).
//
// off(i) = i*(1025-i)/2 ; row i spans [off(i), off(i+1)), length 512-i.

#define ELE 512
#define NPAIRS 131328            // 512*513/2
#define GROUPS 32832             // NPAIRS/4
#define BLOCKS_PER_BATCH 16
#define GROUPS_PER_BLOCK 2052    // GROUPS/BLOCKS_PER_BATCH

__device__ __forceinline__ int row_off(int i) {
    return (i * (1025 - i)) >> 1;
}

__global__ __launch_bounds__(256) void pairmul4_kernel(
    const float* __restrict__ X, float* __restrict__ out) {
    const int bid = blockIdx.x;
    const int b = bid / BLOCKS_PER_BATCH;
    const int c = bid % BLOCKS_PER_BATCH;

    const float* __restrict__ xb = X + (size_t)b * ELE;
    float4* __restrict__ ob = (float4*)(out + (size_t)b * NPAIRS);  // 16B-aligned

    const int glo = c * GROUPS_PER_BLOCK;
    const int ghi = glo + GROUPS_PER_BLOCK;

    for (int g = glo + (int)threadIdx.x; g < ghi; g += 256) {
        const int p = g << 2;
        // Triangular inversion: i = floor((1025 - sqrt(1025^2 - 8p))/2)
        float s = sqrtf((float)(1050625 - 8 * p));
        int i = (int)((1025.0f - s) * 0.5f);
        i = min(max(i, 0), 511);
        int o0 = row_off(i);            // start of row i
        int o1 = o0 + (ELE - i);        // start of row i+1
        while (o1 <= p) { ++i; o0 = o1; o1 += (ELE - i); }
        while (o0 > p)  { --i; o1 = o0; o0 -= (ELE - i); }

        float4 v;
        if (p + 3 < o1) {
            // Fast path: whole group within row i (~98.4% of groups)
            const float xi = xb[i];
            const int j = i + (p - o0);
            v.x = xi * xb[j];
            v.y = xi * xb[j + 1];
            v.z = xi * xb[j + 2];
            v.w = xi * xb[j + 3];
        } else {
            // Group spans a row boundary (rows only get shorter; walk forward)
            float r[4];
            int ii = i, oo0 = o0, oo1 = o1;
            #pragma unroll
            for (int t = 0; t < 4; ++t) {
                const int pt = p + t;
                while (oo1 <= pt) { ++ii; oo0 = oo1; oo1 += (ELE - ii); }
                r[t] = xb[ii] * xb[ii + (pt - oo0)];
            }
            v = make_float4(r[0], r[1], r[2], r[3]);
        }
        ob[g] = v;
    }
}

extern "C" void kernel_launch(void* const* d_in, const int* in_sizes, int n_in,
                              void* d_out, int out_size, void* d_ws, size_t ws_size,
                              hipStream_t stream) {
    const float* X = (const float*)d_in[0];
    float* out = (float*)d_out;

    const int B = in_sizes[0] / ELE;   // 1024
    dim3 grid(B * BLOCKS_PER_BATCH);
    dim3 block(256);
    pairmul4_kernel<<<grid, block, 0, stream>>>(X, out);
}

// Round 5
// 112.059 us; speedup vs baseline: 1.2098x; 1.2098x over previous
//
#include <hip/hip_runtime.h>
#include <hip/hip_bf16.h>

// out[b, p] = x[b, ii[p]] * x[b, jj[p]], (ii,jj)=triu_indices(512), row-major.
// Write-BW-bound: ~538 MB out, 2 MB in. Flat float4-group output indexing with
// triangular inversion (sqrt + fixup). LDS holds 4 SHIFTED COPIES of the row:
// copy c stores x[m+c], so the unaligned 4-run x[j..j+3] is ONE aligned
// ds_read_b128 from copy (j&3) at index (j>>2) — no swizzle VALU, no bank
// conflicts (consecutive lanes read consecutive float4s). Stores are
// non-temporal (pure streaming, never re-read).
//
// off(i) = i*(1025-i)/2 ; row i spans [off(i), off(i+1)), length 512-i.

#define ELE 512
#define NPAIRS 131328            // 512*513/2
#define GROUPS 32832             // NPAIRS/4
#define BPB 8                    // blocks per batch
#define GPB 4104                 // GROUPS/BPB

typedef float f4 __attribute__((ext_vector_type(4)));

__global__ __launch_bounds__(256) void pairmul4_kernel(
    const float* __restrict__ X, float* __restrict__ out) {
    const int bid = blockIdx.x;
    const int b = bid >> 3;        // batch
    const int c = bid & 7;         // chunk within batch

    const float* __restrict__ xb = X + (size_t)b * ELE;
    f4* __restrict__ ob = (f4*)(out + (size_t)b * NPAIRS);  // 16B-aligned

    // 4 shifted copies: xs4[cc][m] = x[m+cc] (0 past end). Row stride 516
    // floats keeps each copy 16B-aligned (516*4 = 2064 = 129*16).
    __shared__ __align__(16) float xs4[4][516];
    const int t = threadIdx.x;
    xs4[0][t]       = xb[t];
    xs4[0][t + 256] = xb[t + 256];
    __syncthreads();
    #pragma unroll
    for (int cc = 1; cc < 4; ++cc) {
        xs4[cc][t]       = xs4[0][t + cc];                            // t+cc < 512 always
        xs4[cc][t + 256] = (t + 256 + cc < ELE) ? xs4[0][t + 256 + cc] : 0.0f;
    }
    __syncthreads();

    const int glo = c * GPB;
    const int ghi = glo + GPB;

    for (int g = glo + t; g < ghi; g += 256) {
        const int p = g << 2;
        // Triangular inversion: i = floor((1025 - sqrt(1025^2 - 8p))/2)
        float s = sqrtf((float)(1050625 - 8 * p));
        int i = (int)((1025.0f - s) * 0.5f);
        i = min(max(i, 0), 511);
        int o0 = (i * (1025 - i)) >> 1;   // start of row i
        int o1 = o0 + (ELE - i);          // start of row i+1
        while (o1 <= p) { ++i; o0 = o1; o1 += (ELE - i); }
        while (o0 > p)  { --i; o1 = o0; o0 -= (ELE - i); }

        f4 v;
        if (p + 3 < o1) {
            // Fast path: whole group within row i (~98.4% of groups)
            const float xi = xs4[0][i];
            const int j = i + (p - o0);
            const f4* yc = (const f4*)(&xs4[j & 3][0]);
            const f4 xv = yc[j >> 2];     // one ds_read_b128, x[j..j+3]
            v = xi * xv;
        } else {
            // Group spans a row boundary (rare; walk forward per element)
            float r[4];
            int ii = i, oo0 = o0, oo1 = o1;
            #pragma unroll
            for (int e = 0; e < 4; ++e) {
                const int pt = p + e;
                while (oo1 <= pt) { ++ii; oo0 = oo1; oo1 += (ELE - ii); }
                r[e] = xs4[0][ii] * xs4[0][ii + (pt - oo0)];
            }
            v.x = r[0]; v.y = r[1]; v.z = r[2]; v.w = r[3];
        }
        __builtin_nontemporal_store(v, &ob[g]);
    }
}

extern "C" void kernel_launch(void* const* d_in, const int* in_sizes, int n_in,
                              void* d_out, int out_size, void* d_ws, size_t ws_size,
                              hipStream_t stream) {
    const float* X = (const float*)d_in[0];
    float* out = (float*)d_out;

    const int B = in_sizes[0] / ELE;   // 1024
    dim3 grid(B * BPB);
    dim3 block(256);
    pairmul4_kernel<<<grid, block, 0, stream>>>(X, out);
}

// Round 7
// 110.612 us; speedup vs baseline: 1.2257x; 1.0131x over previous
//
#include <hip/hip_runtime.h>
#include <hip/hip_bf16.h>

// out[b, p] = x[b, ii[p]] * x[b, jj[p]], (ii,jj)=triu_indices(512), row-major.
// Write-BW-bound: ~538 MB out, 2 MB in.
//
// Branch-free inner loop. Facts used:
//  - off(i) = i*(1025-i)/2; row i spans [off(i), off(i+1)), length 512-i.
//  - Rows 0..508 have length >= 4  =>  a float4 group spans at most TWO rows,
//    with exactly two special cases, both patched via cndmask:
//      * g == GROUPS-1 (rows 509/510/511): element .w is x[511]^2.
//      * g == 255 (i=1, split=3, j1=-1): element .w is x[2]^2. This is the
//        ONLY group where j1 goes negative (row 0 ends 4-aligned; i>=2 has
//        j1 = i+1-split >= 0), so the j1 clamp is otherwise unused.
//  - LDS holds 4 shifted copies (copy c: x[m+c]) so any 4-run x[j..j+3] is one
//    aligned conflict-free ds_read_b128.
// Per group: 2x b128 (row-i run at j0, row-(i+1) run at j1=j0+1-L), 2
// broadcast b32 (xi0, xi1), per-element select on e < o1-p. sqrt inversion
// fixed up with arithmetic selects (+2/-1), no while loops.

#define ELE 512
#define NPAIRS 131328            // 512*513/2
#define GROUPS 32832             // NPAIRS/4
#define BPB 8                    // blocks per batch
#define GPB 4104                 // GROUPS/BPB

typedef float f4 __attribute__((ext_vector_type(4)));

__global__ __launch_bounds__(256) void pairmul4_kernel(
    const float* __restrict__ X, float* __restrict__ out) {
    const int bid = blockIdx.x;
    const int b = bid >> 3;        // batch
    const int c = bid & 7;         // chunk within batch

    const float* __restrict__ xb = X + (size_t)b * ELE;
    f4* __restrict__ ob = (f4*)(out + (size_t)b * NPAIRS);  // 16B-aligned

    // 4 shifted copies, stride 516 floats (2064 B, 16B-aligned rows).
    __shared__ __align__(16) float xs4[4][516];
    const int t = threadIdx.x;
    #pragma unroll
    for (int cc = 0; cc < 4; ++cc) {
        xs4[cc][t] = xb[t + cc];                               // t+cc <= 258 < 512
        const int m1 = t + 256;
        xs4[cc][m1] = (m1 + cc < ELE) ? xb[m1 + cc] : 0.0f;
    }
    if (t < 16) xs4[t & 3][512 + (t >> 2)] = 0.0f;             // pad slots
    __syncthreads();

    const float x511 = xs4[0][511];
    const float lastsq = x511 * x511;                          // pair (511,511)
    const float x2 = xs4[0][2];
    const float g255sq = x2 * x2;                              // pair (2,2)

    const int glo = c * GPB;
    const int ghi = glo + GPB;

    for (int g = glo + t; g < ghi; g += 256) {
        const int p = g << 2;
        // Triangular inversion: i = floor((1025 - sqrt(1025^2 - 8p))/2)
        const float s = sqrtf((float)(1050625 - 8 * p));
        int i = (int)((1025.0f - s) * 0.5f);
        i = min(max(i, 0), 511);
        // Arithmetic fixup (+2 / -1), branch-free:
        int onext = ((i + 1) * (1024 - i)) >> 1;               // off(i+1)
        i += (p >= onext);
        onext = ((i + 1) * (1024 - i)) >> 1;
        i += (p >= onext);
        int ocur = (i * (1025 - i)) >> 1;                      // off(i)
        i -= (p < ocur);

        const int o0 = (i * (1025 - i)) >> 1;
        const int L  = ELE - i;
        const int o1 = o0 + L;

        const int j0 = i + (p - o0);                           // in [0, 511]
        int j1 = j0 + 1 - L;                                   // row-(i+1) run
        j1 = max(j1, 0);                                       // only g==255 clamps (patched)

        const f4 r0 = ((const f4*)xs4[j0 & 3])[j0 >> 2];       // x[j0..j0+3]
        const f4 r1 = ((const f4*)xs4[j1 & 3])[j1 >> 2];       // x[j1..j1+3]
        const float xi0 = xs4[0][i];
        const float xi1 = xs4[0][i + 1];                       // slot 512 zero-padded

        const int split = o1 - p;                              // e < split -> row i
        f4 v;
        v.x = (0 < split) ? xi0 * r0.x : xi1 * r1.x;
        v.y = (1 < split) ? xi0 * r0.y : xi1 * r1.y;
        v.z = (2 < split) ? xi0 * r0.z : xi1 * r1.z;
        v.w = (3 < split) ? xi0 * r0.w : xi1 * r1.w;
        v.w = (g == 255) ? g255sq : v.w;                       // j1=-1 patch
        v.w = (g == GROUPS - 1) ? lastsq : v.w;                // final-group patch
        ob[g] = v;
    }
}

extern "C" void kernel_launch(void* const* d_in, const int* in_sizes, int n_in,
                              void* d_out, int out_size, void* d_ws, size_t ws_size,
                              hipStream_t stream) {
    const float* X = (const float*)d_in[0];
    float* out = (float*)d_out;

    const int B = in_sizes[0] / ELE;   // 1024
    dim3 grid(B * BPB);
    dim3 block(256);
    pairmul4_kernel<<<grid, block, 0, stream>>>(X, out);
}